// Round 4
// baseline (467.163 us; speedup 1.0000x reference)
//
#include <hip/hip_runtime.h>
#include <math.h>

// SatLossEvaluator R4 — low-LDS multisplit binning (direct run writes) +
// split-bucket LDS accumulation with fused float2 gather table.
//
// record u32 = (f_local:11 << 20) | (ef_sign:1 << 19) | (var_idx:19)
// bucket = fun_idx >> 11 (S_FUN=2048, K<=1024); accumulation splits each
// bucket into 2 half-range blocks of 1024 functions (12KB LDS each).
//
// ws: [gcounts K u32][partials 2K double][vpdl V float2][records K*cap u32]

#define THREADS 256
#define S_LOG2  11
#define S_FUN   2048
#define K_MAX   1024
#define HALF    1024
#define TILE    8192

__global__ void fuse_tables(const float* __restrict__ vp,
                            const float* __restrict__ dl,
                            float2* __restrict__ vpdl, int V) {
    int i = blockIdx.x * blockDim.x + threadIdx.x;
    if (i < V) vpdl[i] = make_float2(vp[i], dl[i]);
}

__global__ void __launch_bounds__(THREADS)
bin_edges(const int* __restrict__ gmap,      // [2,E]
          const float* __restrict__ ef,
          unsigned* __restrict__ gcounts,    // K
          unsigned* __restrict__ records,    // K * cap
          int E, int K, int cap) {
    __shared__ unsigned hist[K_MAX], hist2[K_MAX], gbase[K_MAX];

    int base = blockIdx.x * TILE;
    int n = min(TILE, E - base);
    const unsigned* fun = (const unsigned*)(gmap + E) + base;
    const unsigned* var = (const unsigned*)gmap + base;
    const float*    efb = ef + base;

    for (int i = threadIdx.x; i < K; i += THREADS) { hist[i] = 0u; hist2[i] = 0u; }
    __syncthreads();

    // pass 1: bucket histogram (vectorized reads)
    int n4 = n >> 2;
    for (int j = threadIdx.x; j < n4; j += THREADS) {
        uint4 f4 = ((const uint4*)fun)[j];
        atomicAdd(&hist[f4.x >> S_LOG2], 1u);
        atomicAdd(&hist[f4.y >> S_LOG2], 1u);
        atomicAdd(&hist[f4.z >> S_LOG2], 1u);
        atomicAdd(&hist[f4.w >> S_LOG2], 1u);
    }
    for (int j = (n4 << 2) + threadIdx.x; j < n; j += THREADS)
        atomicAdd(&hist[fun[j] >> S_LOG2], 1u);
    __syncthreads();

    // reserve global runs: one atomic per nonzero (bucket, tile)
    for (int b = threadIdx.x; b < K; b += THREADS) {
        unsigned h = hist[b];
        if (h) gbase[b] = atomicAdd(&gcounts[b], h);
    }
    __syncthreads();

    // pass 2: build records, write directly into this tile's reserved runs
    #define EMIT(F_, V_, E_) {                                              \
        unsigned b_  = (F_) >> S_LOG2;                                      \
        unsigned fl_ = (F_) & (S_FUN - 1);                                  \
        unsigned rec_ = (fl_ << 20) | (((E_) < 0.0f ? 1u : 0u) << 19) | (V_);\
        unsigned pos_ = atomicAdd(&hist2[b_], 1u);                          \
        unsigned dst_ = gbase[b_] + pos_;                                   \
        if (dst_ < (unsigned)cap)                                           \
            records[(size_t)b_ * cap + dst_] = rec_; }
    for (int j = threadIdx.x; j < n4; j += THREADS) {
        uint4  f4 = ((const uint4*)fun)[j];
        uint4  v4 = ((const uint4*)var)[j];
        float4 e4 = ((const float4*)efb)[j];
        EMIT(f4.x, v4.x, e4.x); EMIT(f4.y, v4.y, e4.y);
        EMIT(f4.z, v4.z, e4.z); EMIT(f4.w, v4.w, e4.w);
    }
    for (int j = (n4 << 2) + threadIdx.x; j < n; j += THREADS)
        EMIT(fun[j], var[j], efb[j]);
    #undef EMIT
}

__global__ void __launch_bounds__(THREADS)
bucket_accum(const float2* __restrict__ vpdl,
             const unsigned* __restrict__ gcounts,
             const unsigned* __restrict__ records,
             const float* __restrict__ gs,
             const float* __restrict__ mc,
             const float* __restrict__ eps_p,
             const int* __restrict__ ls_p,
             double* __restrict__ partials,
             int F, int cap) {
    __shared__ float accN[HALF], accD[HALF], accT[HALF];
    __shared__ float red[THREADS / 64];

    int bb = blockIdx.x;
    int b = bb >> 1;
    unsigned half = (unsigned)(bb & 1);

    for (int i = threadIdx.x; i < HALF; i += THREADS) {
        accN[i] = 0.0f; accD[i] = 0.0f; accT[i] = 0.0f;
    }
    __syncthreads();

    float coeff = fminf(sqrtf(gs[0]), mc[0]);   // ALPHA = 0.5
    unsigned cnt = gcounts[b];
    if (cnt > (unsigned)cap) cnt = (unsigned)cap;
    const unsigned* rec = records + (size_t)b * cap;

    #define PROC(R_) {                                             \
        unsigned fl_ = (R_) >> 20;                                 \
        if ((fl_ >> 10) == half) {                                 \
            unsigned v_ = (R_) & 0x7FFFFu;                         \
            float e_ = ((R_) >> 19) & 1u ? -1.0f : 1.0f;           \
            float2 t_ = vpdl[v_];                                  \
            float ev_ = e_ * t_.x + (1.0f - e_) * 0.5f;            \
            float w_ = expf(coeff * ev_);                          \
            unsigned s_ = fl_ & (HALF - 1);                        \
            atomicAdd(&accN[s_], w_ * ev_);                        \
            atomicAdd(&accD[s_], w_);                              \
            atomicAdd(&accT[s_], e_ * t_.y); } }
    unsigned n4 = cnt >> 2;
    for (unsigned j = threadIdx.x; j < n4; j += THREADS) {
        uint4 r4 = ((const uint4*)rec)[j];
        PROC(r4.x); PROC(r4.y); PROC(r4.z); PROC(r4.w);
    }
    for (unsigned j = (n4 << 2) + threadIdx.x; j < cnt; j += THREADS)
        PROC(rec[j]);
    #undef PROC
    __syncthreads();

    float epsv = eps_p[0];
    int   ls   = ls_p[0];
    float local = 0.0f;
    int fbase = (b << S_LOG2) + ((int)half << 10);
    for (int i = threadIdx.x; i < HALF; i += THREADS) {
        int fg = fbase + i;
        if (fg < F) {
            float cv = accD[i] / fmaxf(accN[i], epsv);
            float d = cv - 1.0f;
            float p = 1.0f;
            for (int k = 0; k < ls; ++k) p *= d;   // handles d<0 (ls odd)
            cv = accT[i] * (1.0f + p);
            local += logf(fmaxf(cv, epsv));
        }
    }
    #pragma unroll
    for (int off = 32; off > 0; off >>= 1)
        local += __shfl_down(local, off, 64);
    int lane = threadIdx.x & 63, wid = threadIdx.x >> 6;
    if (lane == 0) red[wid] = local;
    __syncthreads();
    if (threadIdx.x == 0) {
        float s = 0.0f;
        #pragma unroll
        for (int w = 0; w < THREADS / 64; ++w) s += red[w];
        partials[bb] = (double)s;
    }
}

__global__ void final_reduce(const double* __restrict__ partials, int nparts,
                             float* __restrict__ out, int F) {
    __shared__ double sm[THREADS];
    double local = 0.0;
    for (int i = threadIdx.x; i < nparts; i += blockDim.x) local += partials[i];
    sm[threadIdx.x] = local;
    __syncthreads();
    for (int s = blockDim.x / 2; s > 0; s >>= 1) {
        if ((int)threadIdx.x < s) sm[threadIdx.x] += sm[threadIdx.x + s];
        __syncthreads();
    }
    if (threadIdx.x == 0) out[0] = (float)(sm[0] / (double)F);
}

extern "C" void kernel_launch(void* const* d_in, const int* in_sizes, int n_in,
                              void* d_out, int out_size, void* d_ws, size_t ws_size,
                              hipStream_t stream) {
    const float* vp   = (const float*)d_in[0];
    const float* dl   = (const float*)d_in[1];
    const int*   gmap = (const int*)d_in[3];
    const float* ef   = (const float*)d_in[6];
    const float* gs   = (const float*)d_in[8];
    const float* eps  = (const float*)d_in[9];
    const float* mc   = (const float*)d_in[10];
    const int*   ls   = (const int*)d_in[11];

    const int V = in_sizes[0];
    const int F = in_sizes[5];
    const int E = in_sizes[6];
    const int K = (F + S_FUN - 1) / S_FUN;   // 977 at F=2M

    size_t off = 0;
    unsigned* gcounts = (unsigned*)d_ws;
    off = ((size_t)K * sizeof(unsigned) + 15) & ~(size_t)15;
    double* partials = (double*)((char*)d_ws + off);
    off = (off + (size_t)(2 * K) * sizeof(double) + 15) & ~(size_t)15;
    float2* vpdl = (float2*)((char*)d_ws + off);
    off = (off + (size_t)V * sizeof(float2) + 15) & ~(size_t)15;
    unsigned* records = (unsigned*)((char*)d_ws + off);

    size_t avail = ws_size > off ? ws_size - off : 0;
    long long cap = (long long)(avail / ((size_t)K * sizeof(unsigned)));
    if (cap > 16384) cap = 16384;    // mean E/K ~8.2K + 87 sigma headroom
    cap &= ~3LL;                     // 16B-aligned bucket bases for uint4
    if (cap < 4) cap = 4;

    hipMemsetAsync(gcounts, 0, (size_t)K * sizeof(unsigned), stream);

    fuse_tables<<<(V + THREADS - 1) / THREADS, THREADS, 0, stream>>>(vp, dl, vpdl, V);

    int tiles = (E + TILE - 1) / TILE;
    bin_edges<<<tiles, THREADS, 0, stream>>>(gmap, ef, gcounts, records,
                                             E, K, (int)cap);

    bucket_accum<<<2 * K, THREADS, 0, stream>>>(vpdl, gcounts, records,
                                                gs, mc, eps, ls, partials,
                                                F, (int)cap);

    final_reduce<<<1, THREADS, 0, stream>>>(partials, 2 * K, (float*)d_out, F);
}

// Round 5
// 369.653 us; speedup vs baseline: 1.2638x; 1.2638x over previous
//
#include <hip/hip_runtime.h>
#include <math.h>

// SatLossEvaluator R5 — staged multisplit binning (R3 structure, less LDS) +
// record-range-split bucket accumulation + separate combine/epilogue kernel.
//
// record u32 = (f_local:11 << 20) | (ef_sign:1 << 19) | (var_idx:19)
// bucket = fun_idx >> 11 (S_FUN=2048, K<=1024)
// ws: [gcounts K u32][partials K double][vpdl V float2]
//     [pacc K*nsplit*3*S_FUN f32][records K*cap u32]

#define THREADS 256
#define S_LOG2  11
#define S_FUN   2048
#define K_MAX   1024
#define TILE    8192

__global__ void fuse_tables(const float* __restrict__ vp,
                            const float* __restrict__ dl,
                            float2* __restrict__ vpdl, int V) {
    int i = blockIdx.x * blockDim.x + threadIdx.x;
    if (i < V) vpdl[i] = make_float2(vp[i], dl[i]);
}

__global__ void __launch_bounds__(THREADS)
bin_edges(const int* __restrict__ gmap,      // [2,E]
          const float* __restrict__ ef,
          unsigned* __restrict__ gcounts,    // K
          unsigned* __restrict__ records,    // K * cap
          int E, int K, int cap) {
    __shared__ unsigned hist[K_MAX];   // histogram, then pass-2 counter
    __shared__ unsigned offs[K_MAX];   // exclusive scan (ascending)
    __shared__ unsigned gbase[K_MAX];  // global run base per bucket
    __shared__ unsigned staging[TILE]; // bucket-contiguous records
    __shared__ unsigned wred[THREADS / 64];

    int base = blockIdx.x * TILE;
    int n = min(TILE, E - base);
    const unsigned* fun = (const unsigned*)(gmap + E) + base;
    const unsigned* var = (const unsigned*)gmap + base;
    const float*    efb = ef + base;

    for (int i = threadIdx.x; i < K; i += THREADS) hist[i] = 0u;
    __syncthreads();

    // pass 1: bucket histogram (vectorized)
    int n4 = n >> 2;
    for (int j = threadIdx.x; j < n4; j += THREADS) {
        uint4 f4 = ((const uint4*)fun)[j];
        atomicAdd(&hist[f4.x >> S_LOG2], 1u);
        atomicAdd(&hist[f4.y >> S_LOG2], 1u);
        atomicAdd(&hist[f4.z >> S_LOG2], 1u);
        atomicAdd(&hist[f4.w >> S_LOG2], 1u);
    }
    for (int j = (n4 << 2) + threadIdx.x; j < n; j += THREADS)
        atomicAdd(&hist[fun[j] >> S_LOG2], 1u);
    __syncthreads();

    // reserve global runs (one atomic per nonzero bucket per tile)
    for (int b = threadIdx.x; b < K; b += THREADS) {
        unsigned h = hist[b];
        if (h) gbase[b] = atomicAdd(&gcounts[b], h);
    }

    // exclusive scan hist -> offs (4 per thread; wave scan + wave bases)
    {
        int t4 = threadIdx.x * 4;
        unsigned a0 = (t4 + 0 < K) ? hist[t4 + 0] : 0u;
        unsigned a1 = (t4 + 1 < K) ? hist[t4 + 1] : 0u;
        unsigned a2 = (t4 + 2 < K) ? hist[t4 + 2] : 0u;
        unsigned a3 = (t4 + 3 < K) ? hist[t4 + 3] : 0u;
        unsigned s = a0 + a1 + a2 + a3;
        unsigned sc = s;
        int lane = threadIdx.x & 63, wid = threadIdx.x >> 6;
        #pragma unroll
        for (int d = 1; d < 64; d <<= 1) {
            unsigned t = __shfl_up(sc, d, 64);
            if (lane >= d) sc += t;
        }
        if (lane == 63) wred[wid] = sc;
        __syncthreads();
        unsigned wb = 0;
        for (int w = 0; w < wid; ++w) wb += wred[w];
        unsigned ex = wb + sc - s;
        if (t4 + 0 < K) { offs[t4 + 0] = ex; ex += a0; }
        if (t4 + 1 < K) { offs[t4 + 1] = ex; ex += a1; }
        if (t4 + 2 < K) { offs[t4 + 2] = ex; ex += a2; }
        if (t4 + 3 < K) { offs[t4 + 3] = ex; ex += a3; }
    }
    __syncthreads();
    for (int i = threadIdx.x; i < K; i += THREADS) hist[i] = 0u;  // -> counter
    __syncthreads();

    // pass 2: build records, place bucket-contiguous in staging
    #define EMIT(F_, V_, E_) {                                               \
        unsigned b_  = (F_) >> S_LOG2;                                       \
        unsigned rec_ = (((F_) & (S_FUN - 1)) << 20) |                       \
                        (((E_) < 0.0f ? 1u : 0u) << 19) | (V_);              \
        unsigned pos_ = atomicAdd(&hist[b_], 1u);                            \
        staging[offs[b_] + pos_] = rec_; }
    for (int j = threadIdx.x; j < n4; j += THREADS) {
        uint4  f4 = ((const uint4*)fun)[j];
        uint4  v4 = ((const uint4*)var)[j];
        float4 e4 = ((const float4*)efb)[j];
        EMIT(f4.x, v4.x, e4.x); EMIT(f4.y, v4.y, e4.y);
        EMIT(f4.z, v4.z, e4.z); EMIT(f4.w, v4.w, e4.w);
    }
    for (int j = (n4 << 2) + threadIdx.x; j < n; j += THREADS)
        EMIT(fun[j], var[j], efb[j]);
    #undef EMIT
    __syncthreads();

    // copy out: consecutive staging slots -> consecutive global slots per run.
    // bucket of slot j = largest b with offs[b] <= j (binary search, 10 steps)
    for (int j = threadIdx.x; j < n; j += THREADS) {
        unsigned rec = staging[j];
        int lo = 0, hi = K - 1;
        while (lo < hi) {
            int mid = (lo + hi + 1) >> 1;
            if (offs[mid] <= (unsigned)j) lo = mid; else hi = mid - 1;
        }
        unsigned dst = gbase[lo] + ((unsigned)j - offs[lo]);
        if (dst < (unsigned)cap)                       // drop-guard (never hit)
            records[(size_t)lo * cap + dst] = rec;
    }
}

__global__ void __launch_bounds__(THREADS)
bucket_accum(const float2* __restrict__ vpdl,
             const unsigned* __restrict__ gcounts,
             const unsigned* __restrict__ records,
             const float* __restrict__ gs,
             const float* __restrict__ mc,
             float* __restrict__ pacc,     // [K*nsplit][3][S_FUN]
             int nsplit, int cap) {
    __shared__ float accN[S_FUN], accD[S_FUN], accT[S_FUN];

    int bb = blockIdx.x;
    int b = bb / nsplit;
    int h = bb - b * nsplit;

    for (int i = threadIdx.x; i < S_FUN; i += THREADS) {
        accN[i] = 0.0f; accD[i] = 0.0f; accT[i] = 0.0f;
    }
    __syncthreads();

    float coeff = fminf(sqrtf(gs[0]), mc[0]);   // ALPHA = 0.5
    unsigned cnt = gcounts[b];
    if (cnt > (unsigned)cap) cnt = (unsigned)cap;
    // split by record range, 16B-aligned boundary
    unsigned halfpt = (nsplit == 2) ? min(cnt, (((cnt + 1) >> 1) + 3u) & ~3u) : cnt;
    unsigned start = (h == 0) ? 0u : halfpt;
    unsigned end   = (h == 0) ? halfpt : cnt;
    const unsigned* rec = records + (size_t)b * cap;

    #define PROC(R_) {                                             \
        unsigned v_ = (R_) & 0x7FFFFu;                             \
        float e_ = ((R_) >> 19) & 1u ? -1.0f : 1.0f;               \
        unsigned s_ = (R_) >> 20;                                  \
        float2 t_ = vpdl[v_];                                      \
        float ev_ = e_ * t_.x + (1.0f - e_) * 0.5f;                \
        float w_ = expf(coeff * ev_);                              \
        atomicAdd(&accN[s_], w_ * ev_);                            \
        atomicAdd(&accD[s_], w_);                                  \
        atomicAdd(&accT[s_], e_ * t_.y); }
    unsigned i0 = start >> 2, i1 = end >> 2;
    for (unsigned j = i0 + threadIdx.x; j < i1; j += THREADS) {
        uint4 r4 = ((const uint4*)rec)[j];
        PROC(r4.x); PROC(r4.y); PROC(r4.z); PROC(r4.w);
    }
    for (unsigned j = (i1 << 2) + threadIdx.x; j < end; j += THREADS)
        PROC(rec[j]);
    #undef PROC
    __syncthreads();

    // write partial accumulators (coalesced float4)
    float* out = pacc + (size_t)bb * 3 * S_FUN;
    for (int i = threadIdx.x; i < S_FUN / 4; i += THREADS) {
        ((float4*)out)[i]                 = ((float4*)accN)[i];
        ((float4*)(out + S_FUN))[i]       = ((float4*)accD)[i];
        ((float4*)(out + 2 * S_FUN))[i]   = ((float4*)accT)[i];
    }
}

__global__ void __launch_bounds__(THREADS)
combine_loss(const float* __restrict__ pacc,
             const float* __restrict__ eps_p,
             const int* __restrict__ ls_p,
             double* __restrict__ partials,
             int F, int nsplit) {
    __shared__ float red[THREADS / 64];
    int b = blockIdx.x;
    float epsv = eps_p[0];
    int   ls   = ls_p[0];
    float local = 0.0f;

    for (int i = threadIdx.x; i < S_FUN / 4; i += THREADS) {
        float4 N = make_float4(0, 0, 0, 0), D = N, T = N;
        for (int s = 0; s < nsplit; ++s) {
            const float* p = pacc + (size_t)(b * nsplit + s) * 3 * S_FUN;
            float4 n4 = ((const float4*)p)[i];
            float4 d4 = ((const float4*)(p + S_FUN))[i];
            float4 t4 = ((const float4*)(p + 2 * S_FUN))[i];
            N.x += n4.x; N.y += n4.y; N.z += n4.z; N.w += n4.w;
            D.x += d4.x; D.y += d4.y; D.z += d4.z; D.w += d4.w;
            T.x += t4.x; T.y += t4.y; T.z += t4.z; T.w += t4.w;
        }
        float ns[4] = {N.x, N.y, N.z, N.w};
        float ds[4] = {D.x, D.y, D.z, D.w};
        float ts[4] = {T.x, T.y, T.z, T.w};
        int fbase = (b << S_LOG2) + (i << 2);
        #pragma unroll
        for (int c = 0; c < 4; ++c) {
            if (fbase + c < F) {
                float cv = ds[c] / fmaxf(ns[c], epsv);
                float d = cv - 1.0f;
                float p = 1.0f;
                for (int k = 0; k < ls; ++k) p *= d;   // handles d<0 (ls odd)
                cv = ts[c] * (1.0f + p);
                local += logf(fmaxf(cv, epsv));
            }
        }
    }
    #pragma unroll
    for (int off = 32; off > 0; off >>= 1)
        local += __shfl_down(local, off, 64);
    int lane = threadIdx.x & 63, wid = threadIdx.x >> 6;
    if (lane == 0) red[wid] = local;
    __syncthreads();
    if (threadIdx.x == 0) {
        float s = 0.0f;
        #pragma unroll
        for (int w = 0; w < THREADS / 64; ++w) s += red[w];
        partials[b] = (double)s;
    }
}

__global__ void final_reduce(const double* __restrict__ partials, int nparts,
                             float* __restrict__ out, int F) {
    __shared__ double sm[THREADS];
    double local = 0.0;
    for (int i = threadIdx.x; i < nparts; i += blockDim.x) local += partials[i];
    sm[threadIdx.x] = local;
    __syncthreads();
    for (int s = blockDim.x / 2; s > 0; s >>= 1) {
        if ((int)threadIdx.x < s) sm[threadIdx.x] += sm[threadIdx.x + s];
        __syncthreads();
    }
    if (threadIdx.x == 0) out[0] = (float)(sm[0] / (double)F);
}

extern "C" void kernel_launch(void* const* d_in, const int* in_sizes, int n_in,
                              void* d_out, int out_size, void* d_ws, size_t ws_size,
                              hipStream_t stream) {
    const float* vp   = (const float*)d_in[0];
    const float* dl   = (const float*)d_in[1];
    const int*   gmap = (const int*)d_in[3];
    const float* ef   = (const float*)d_in[6];
    const float* gs   = (const float*)d_in[8];
    const float* eps  = (const float*)d_in[9];
    const float* mc   = (const float*)d_in[10];
    const int*   ls   = (const int*)d_in[11];

    const int V = in_sizes[0];
    const int F = in_sizes[5];
    const int E = in_sizes[6];
    const int K = (F + S_FUN - 1) / S_FUN;   // 977 at F=2M

    size_t off = ((size_t)K * sizeof(unsigned) + 15) & ~(size_t)15;
    unsigned* gcounts = (unsigned*)d_ws;
    double* partials = (double*)((char*)d_ws + off);
    off = (off + (size_t)K * sizeof(double) + 15) & ~(size_t)15;
    float2* vpdl = (float2*)((char*)d_ws + off);
    off = (off + (size_t)V * sizeof(float2) + 15) & ~(size_t)15;

    // choose nsplit=2 if ws allows pacc + comfortable record capacity
    int nsplit = 2;
    size_t pacc_bytes = (size_t)K * nsplit * 3 * S_FUN * sizeof(float);
    size_t rec_off = off + ((pacc_bytes + 15) & ~(size_t)15);
    long long cap = (ws_size > rec_off)
        ? (long long)((ws_size - rec_off) / ((size_t)K * sizeof(unsigned))) : 0;
    if (cap < 12288) {   // fall back to single-block buckets
        nsplit = 1;
        pacc_bytes = (size_t)K * 3 * S_FUN * sizeof(float);
        rec_off = off + ((pacc_bytes + 15) & ~(size_t)15);
        cap = (ws_size > rec_off)
            ? (long long)((ws_size - rec_off) / ((size_t)K * sizeof(unsigned))) : 4;
    }
    if (cap > 16384) cap = 16384;   // mean E/K ~8.2K, sigma ~90
    cap &= ~3LL;
    if (cap < 4) cap = 4;

    float* pacc = (float*)((char*)d_ws + off);
    unsigned* records = (unsigned*)((char*)d_ws + rec_off);

    hipMemsetAsync(gcounts, 0, (size_t)K * sizeof(unsigned), stream);

    fuse_tables<<<(V + THREADS - 1) / THREADS, THREADS, 0, stream>>>(vp, dl, vpdl, V);

    int tiles = (E + TILE - 1) / TILE;
    bin_edges<<<tiles, THREADS, 0, stream>>>(gmap, ef, gcounts, records,
                                             E, K, (int)cap);

    bucket_accum<<<K * nsplit, THREADS, 0, stream>>>(vpdl, gcounts, records,
                                                     gs, mc, pacc, nsplit, (int)cap);

    combine_loss<<<K, THREADS, 0, stream>>>(pacc, eps, ls, partials, F, nsplit);

    final_reduce<<<1, THREADS, 0, stream>>>(partials, K, (float*)d_out, F);
}